// Round 24
// baseline (98.580 us; speedup 1.0000x reference)
//
#include <hip/hip_runtime.h>

// EntailmentSelfAttention: N=16, L=256, S=2, H=16, D=64, E=1024
//
// Pipeline (4 kernels):
//   K0 k_wot  : Wb[f][e'] = bf16(Wo[f][perm(e')]) (frozen, r17).
//   K1 k_proj : v4 streaming MFMA, grid 1024 (l split in halves).
//               r23: 50us with grid 512 = 2 blocks/CU exactly, Occ 28%,
//               ~3.2 B/cyc/CU (3x below HBM-bound rate) - concurrency
//               starved, not pattern-starved (FETCH 50MB, lines unique).
//               Now: block = (nhs, lhalf of 128 rows), 512 thr = 8 waves,
//               wave = one 16-row l-tile. 27.6KB LDS -> 4 blocks/CU,
//               up to 32 waves/CU (2x r23).
//   K2 k_attn : fused stats+PV MFMA v2 (frozen, r21).
//   K3 k_wo   : bf16 MFMA GEMM (frozen, r17).
//
// ws layout (f32-elem offsets): kB @0, qB @4194304, vB @8388608,
//   Xb @12582912, Wb @16777216.

typedef __attribute__((ext_vector_type(8))) short bf16x8;
typedef __attribute__((ext_vector_type(4))) float f32x4;

__device__ inline ushort f2bf(float x) {
    uint u = __float_as_uint(x);
    u += 0x7FFFu + ((u >> 16) & 1u);
    return (ushort)(u >> 16);
}

__global__ __launch_bounds__(256) void k_wot(
    const float* __restrict__ Wo, ushort* __restrict__ Wb)
{
    const int f = blockIdx.x;          // 0..1023
    const int e4 = threadIdx.x * 4;    // e' base (d%4==0, fixed hr/sp)
    const int hr = e4 >> 7, sp = (e4 >> 6) & 1, d = e4 & 63;
    const float* wrow = Wo + (long)f * 1024 + hr * 128 + 2 * d + sp;
    ushort o[4] = {f2bf(wrow[0]), f2bf(wrow[2]), f2bf(wrow[4]), f2bf(wrow[6])};
    *(uint2*)(Wb + (long)f * 1024 + e4) = *(uint2*)o;
}

// Streaming MFMA projections v4: block = (nhs, lhalf of 128 l); 512 thr =
// 8 waves; wave owns one 16-row l-tile. A-op = W (LDS), B-op = A rows
// (global direct). D col=l,row=e -> uint2 stores. One barrier total.
__global__ __launch_bounds__(512) void k_proj(
    const float* __restrict__ Av, const float* __restrict__ Ak,
    const float* __restrict__ Aq, const float* __restrict__ Wv,
    const float* __restrict__ Wk, const float* __restrict__ Wq,
    ushort* __restrict__ kB, ushort* __restrict__ qB,
    ushort* __restrict__ vB)
{
    __shared__ ushort Wsb[3][64][72];   // 27,648 B  [m][e][d]
    const int b = blockIdx.x;
    const int nhs = b >> 1, lhalf = b & 1;
    const int n = nhs >> 5, h = (nhs >> 1) & 15, s = nhs & 1;
    const float* Asrc[3] = {Av, Ak, Aq};
    const float* Wsrc[3] = {Wv, Wk, Wq};
    const int tid = threadIdx.x;
    const int wid = tid >> 6, lane = tid & 63;
    const int lr = lane & 15, lk = lane >> 4;

    const long abase = (long)n * 524288 + s * 1024 + h * 64;
    const long slice = ((long)nhs) * 16384;
    ushort* Bdst[3] = {vB, kB, qB};

    // stage all 3 W matrices once (f32 -> bf16): 1024 chunks/m, 512 thr
#pragma unroll
    for (int m = 0; m < 3; ++m)
#pragma unroll
        for (int w = 0; w < 2; ++w) {
            int idx = w * 512 + tid;
            int r = idx >> 4, c4 = (idx & 15) * 4;
            float4 v = *(const float4*)(Wsrc[m] + r * 64 + c4);
            ushort t4[4] = {f2bf(v.x), f2bf(v.y), f2bf(v.z), f2bf(v.w)};
            *(uint2*)&Wsb[m][r][c4] = *(uint2*)t4;
        }
    __syncthreads();   // the only barrier

    const int lrow = lhalf * 128 + wid * 16 + lr;
    const float* arow0 = Av + abase + (long)lrow * 2048;
    const float* arow1 = Ak + abase + (long)lrow * 2048;
    const float* arow2 = Aq + abase + (long)lrow * 2048;
    const float* arows[3] = {arow0, arow1, arow2};
    (void)Asrc;

#pragma unroll 1
    for (int m = 0; m < 3; ++m) {
        const float* arow = arows[m];
        ushort* B = Bdst[m];
        // B-op frags direct from global (col=l -> lane's own row)
        bf16x8 bfrag[2];
#pragma unroll
        for (int ks = 0; ks < 2; ++ks) {
            float4 v0 = *(const float4*)(arow + ks * 32 + lk * 8);
            float4 v1 = *(const float4*)(arow + ks * 32 + lk * 8 + 4);
            ushort t8[8] = {f2bf(v0.x), f2bf(v0.y), f2bf(v0.z), f2bf(v0.w),
                            f2bf(v1.x), f2bf(v1.y), f2bf(v1.z), f2bf(v1.w)};
            bfrag[ks] = *(bf16x8*)t8;
        }
#pragma unroll
        for (int et = 0; et < 4; ++et) {
            f32x4 acc;
#pragma unroll
            for (int rg = 0; rg < 4; ++rg) acc[rg] = 0.f;
#pragma unroll
            for (int ks = 0; ks < 2; ++ks) {
                bf16x8 wfrag = *(const bf16x8*)
                    &Wsb[m][et * 16 + lr][ks * 32 + lk * 8];
                acc = __builtin_amdgcn_mfma_f32_16x16x32_bf16(
                    wfrag, bfrag[ks], acc, 0, 0, 0);
            }
            // D: col=l=lrow (lane's lr), row=e=et*16+lk*4+rg
            ushort t4[4] = {f2bf(acc[0]), f2bf(acc[1]),
                            f2bf(acc[2]), f2bf(acc[3])};
            *(uint2*)(B + slice + (long)lrow * 64 + et * 16 + lk * 4) =
                *(uint2*)t4;
        }
    }
}

// Fused stats+PV v2 (frozen, r21): one block per nhs, 512 thr = 8 waves.
__global__ __launch_bounds__(512) void k_attn(
    const ushort* __restrict__ kB, const ushort* __restrict__ qB,
    const ushort* __restrict__ vB, const int* __restrict__ mask,
    ushort* __restrict__ Xb)
{
    __shared__ ushort Ks[32][72];     //  4,608 B  [l][k]
    __shared__ ushort vsT[64][44];    //  5,632 B  [d][l]
    __shared__ ushort Es[128][44];    // 11,264 B  [wave-q][l]
    __shared__ float Zl[256];         //  1,024 B
    __shared__ int mb16[16];
    const int nhs = blockIdx.x;
    const int n = nhs >> 5, h = (nhs >> 1) & 15, s = nhs & 1;
    const long slice = (long)nhs * 16384;
    const int tid = threadIdx.x;
    const int wid = tid >> 6, lane = tid & 63;
    const int lr = lane & 15, lk = lane >> 4;

    bf16x8 aq[2][2];
#pragma unroll
    for (int qt = 0; qt < 2; ++qt) {
        const int qb = wid * 32 + qt * 16;
        aq[qt][0] = *(const bf16x8*)(qB + slice + (qb + lr) * 64 + lk * 8);
        aq[qt][1] = *(const bf16x8*)(qB + slice + (qb + lr) * 64 + 32 + lk * 8);
    }
    const int mrow = n * 524288 + (h >> 3) * 262144 + (h & 7) * 32 + s * 16;
    if (tid < 16) mb16[tid] = mask[mrow + tid];
    if (tid < 256) Zl[tid] = 0.f;

    const float scale = 0.03125f;

    // ========== PHASE 1: Z accumulation ==========
#pragma unroll 1
    for (int sl = 0; sl < 8; ++sl) {
        __syncthreads();
        if (tid < 256) {
            int r = tid >> 3, c8 = (tid & 7) * 8;
            *(uint4*)&Ks[r][c8] =
                *(const uint4*)(kB + slice + (sl * 32 + r) * 64 + c8);
        }
        __syncthreads();

        float zlt[2] = {0.f, 0.f};
#pragma unroll
        for (int qt = 0; qt < 2; ++qt) {
            const int qb = wid * 32 + qt * 16;
            if (mb16[qb >> 4] == 0) continue;
#pragma unroll
            for (int lt = 0; lt < 2; ++lt) {
                f32x4 sacc;
#pragma unroll
                for (int rg = 0; rg < 4; ++rg) sacc[rg] = 0.f;
                bf16x8 b0 = *(const bf16x8*)&Ks[lt * 16 + lr][lk * 8];
                bf16x8 b1 = *(const bf16x8*)&Ks[lt * 16 + lr][32 + lk * 8];
                sacc = __builtin_amdgcn_mfma_f32_16x16x32_bf16(
                    aq[qt][0], b0, sacc, 0, 0, 0);
                sacc = __builtin_amdgcn_mfma_f32_16x16x32_bf16(
                    aq[qt][1], b1, sacc, 0, 0, 0);
#pragma unroll
                for (int rg = 0; rg < 4; ++rg)
                    zlt[lt] += __expf(sacc[rg] * scale);
            }
        }
#pragma unroll
        for (int lt = 0; lt < 2; ++lt) {
            float v = zlt[lt];
            v += __shfl_xor(v, 16);
            v += __shfl_xor(v, 32);
            if (lk == 0)
                atomicAdd(&Zl[sl * 32 + lt * 16 + lr], v);
        }
    }

    __syncthreads();
    if (tid < 256) {
        float z = Zl[tid];
        Zl[tid] = (z > 0.f) ? 1.0f / z : 1.0f / 256.0f;
    }

    // ========== PHASE 2: att + PV ==========
    f32x4 acc0[4], acc1[4];
#pragma unroll
    for (int dt = 0; dt < 4; ++dt)
#pragma unroll
        for (int rg = 0; rg < 4; ++rg) { acc0[dt][rg] = 0.f; acc1[dt][rg] = 0.f; }

#pragma unroll 1
    for (int sl = 0; sl < 8; ++sl) {
        __syncthreads();
        if (tid < 256) {
            int r = tid >> 3, c8 = (tid & 7) * 8;
            *(uint4*)&Ks[r][c8] =
                *(const uint4*)(kB + slice + (sl * 32 + r) * 64 + c8);
        } else {
            int t = tid - 256;
            int l = t >> 3, d8 = (t & 7) * 8;
            uint4 vv = *(const uint4*)(vB + slice + (sl * 32 + l) * 64 + d8);
            ushort t8[8];
            *(uint4*)t8 = vv;
#pragma unroll
            for (int u = 0; u < 8; ++u) vsT[d8 + u][l] = t8[u];
        }
        __syncthreads();

#pragma unroll
        for (int qt = 0; qt < 2; ++qt) {
            const int qb = wid * 32 + qt * 16;
            const bool live = (mb16[qb >> 4] != 0);
#pragma unroll
            for (int lt = 0; lt < 2; ++lt) {
                f32x4 sacc;
#pragma unroll
                for (int rg = 0; rg < 4; ++rg) sacc[rg] = 0.f;
                bf16x8 b0 = *(const bf16x8*)&Ks[lt * 16 + lr][lk * 8];
                bf16x8 b1 = *(const bf16x8*)&Ks[lt * 16 + lr][32 + lk * 8];
                sacc = __builtin_amdgcn_mfma_f32_16x16x32_bf16(
                    aq[qt][0], b0, sacc, 0, 0, 0);
                sacc = __builtin_amdgcn_mfma_f32_16x16x32_bf16(
                    aq[qt][1], b1, sacc, 0, 0, 0);
                const int l = lt * 16 + lr;
                const float iz = Zl[sl * 32 + l];
#pragma unroll
                for (int rg = 0; rg < 4; ++rg) {
                    float ev = live ? __expf(sacc[rg] * scale) * iz : 0.f;
                    Es[wid * 16 + lk * 4 + rg][l] = f2bf(ev);
                }
            }
            __builtin_amdgcn_s_waitcnt(0);  // lgkmcnt(0): wave-local Es
            bf16x8 aP = *(const bf16x8*)&Es[wid * 16 + lr][lk * 8];
            f32x4* accp = (qt == 0) ? acc0 : acc1;
#pragma unroll
            for (int dt = 0; dt < 4; ++dt) {
                bf16x8 bV = *(const bf16x8*)&vsT[dt * 16 + lr][lk * 8];
                accp[dt] = __builtin_amdgcn_mfma_f32_16x16x32_bf16(
                    aP, bV, accp[dt], 0, 0, 0);
            }
        }
    }

#pragma unroll
    for (int qt = 0; qt < 2; ++qt) {
        const f32x4* accp = (qt == 0) ? acc0 : acc1;
        const int qb = wid * 32 + qt * 16;
#pragma unroll
        for (int dt = 0; dt < 4; ++dt) {
#pragma unroll
            for (int rg = 0; rg < 4; ++rg) {
                const int q = qb + lk * 4 + rg;
                const int d = dt * 16 + lr;
                Xb[slice + (long)q * 64 + d] = f2bf(accp[dt][rg]);
            }
        }
    }
}

// MFMA k_wo (frozen, r17).
__global__ __launch_bounds__(512) void k_wo(
    const ushort* __restrict__ Xb, const ushort* __restrict__ Wb,
    const float* __restrict__ bo, float* __restrict__ out)
{
    __shared__ ushort Xs[128][72];
    __shared__ ushort Ws[128][72];
    const int b = blockIdx.x;
    const int by = b >> 3, bx = b & 7;
    const int r0 = by * 128, f0 = bx * 128;
    const int tid = threadIdx.x;
    const int wid = tid >> 6, lane = tid & 63;
    const int wr = wid >> 2, wc = wid & 3;
    const int lr = lane & 15, lk = lane >> 4;

    f32x4 acc[4][2];
#pragma unroll
    for (int rt = 0; rt < 4; ++rt)
#pragma unroll
        for (int ft = 0; ft < 2; ++ft)
#pragma unroll
            for (int rg = 0; rg < 4; ++rg) acc[rt][ft][rg] = 0.f;

    const int sr = tid >> 2, sc = (tid & 3) * 16;
    const int sR = r0 + sr;
    const int sn = sR >> 9, sq = (sR >> 1) & 255, ss2 = sR & 1;

#pragma unroll 1
    for (int eo = 0; eo < 1024; eo += 64) {
        const int hr = eo >> 7, sp = (eo >> 6) & 1;
        __syncthreads();
        {
            long xo = ((long)((sn * 16 + (ss2 * 8 + hr)) * 2 + sp)) * 16384 +
                      sq * 64 + sc;
            *(uint4*)&Xs[sr][sc] = *(const uint4*)(Xb + xo);
            *(uint4*)&Xs[sr][sc + 8] = *(const uint4*)(Xb + xo + 8);
            long wo = (long)(f0 + sr) * 1024 + eo + sc;
            *(uint4*)&Ws[sr][sc] = *(const uint4*)(Wb + wo);
            *(uint4*)&Ws[sr][sc + 8] = *(const uint4*)(Wb + wo + 8);
        }
        __syncthreads();

#pragma unroll
        for (int ks = 0; ks < 2; ++ks) {
            bf16x8 a[4], bb[2];
#pragma unroll
            for (int rt = 0; rt < 4; ++rt)
                a[rt] = *(const bf16x8*)
                    &Xs[wr * 64 + rt * 16 + lr][ks * 32 + lk * 8];
#pragma unroll
            for (int ft = 0; ft < 2; ++ft)
                bb[ft] = *(const bf16x8*)
                    &Ws[wc * 32 + ft * 16 + lr][ks * 32 + lk * 8];
#pragma unroll
            for (int rt = 0; rt < 4; ++rt)
#pragma unroll
                for (int ft = 0; ft < 2; ++ft)
                    acc[rt][ft] = __builtin_amdgcn_mfma_f32_16x16x32_bf16(
                        a[rt], bb[ft], acc[rt][ft], 0, 0, 0);
        }
    }

#pragma unroll
    for (int ft = 0; ft < 2; ++ft) {
        const int f = f0 + wc * 32 + ft * 16 + lr;
        const float bias = bo[f];
#pragma unroll
        for (int rt = 0; rt < 4; ++rt) {
#pragma unroll
            for (int rg = 0; rg < 4; ++rg) {
                const int r = r0 + wr * 64 + rt * 16 + lk * 4 + rg;
                out[(long)r * 1024 + f] = acc[rt][ft][rg] + bias;
            }
        }
    }
}

extern "C" void kernel_launch(void* const* d_in, const int* in_sizes, int n_in,
                              void* d_out, int out_size, void* d_ws,
                              size_t ws_size, hipStream_t stream)
{
    const float* vals = (const float*)d_in[0];
    const float* keys = (const float*)d_in[1];
    const float* qrys = (const float*)d_in[2];
    const int*   mask = (const int*)d_in[3];
    const float* Wv   = (const float*)d_in[4];
    const float* Wk   = (const float*)d_in[5];
    const float* Wq   = (const float*)d_in[6];
    const float* Wo   = (const float*)d_in[7];
    const float* bo   = (const float*)d_in[8];
    float* ws  = (float*)d_ws;
    ushort* kB = (ushort*)(ws);
    ushort* qB = (ushort*)(ws + 4194304);
    ushort* vB = (ushort*)(ws + 8388608);
    ushort* Xb = (ushort*)(ws + 12582912);
    ushort* Wb = (ushort*)(ws + 16777216);
    float* out = (float*)d_out;

    k_wot <<<1024, 256, 0, stream>>>(Wo, Wb);
    k_proj<<<1024, 512, 0, stream>>>(vals, keys, qrys, Wv, Wk, Wq, kB, qB, vB);
    k_attn<<< 512, 512, 0, stream>>>(kB, qB, vB, mask, Xb);
    k_wo  <<< 512, 512, 0, stream>>>(Xb, Wb, bo, out);
}